// Round 1
// baseline (324.893 us; speedup 1.0000x reference)
//
#include <hip/hip_runtime.h>
#include <hip/hip_bf16.h>

#define T_SEQ 4096
#define HDIM  64
#define QBLK  128
#define KVBLK 64
#define PAD   72   // LDS row stride (bf16 elems): 144 B rows -> 16B-aligned, 2-way-conflict reads (free)

typedef __attribute__((ext_vector_type(8))) short  short8;
typedef __attribute__((ext_vector_type(8))) __bf16 bf16x8;
typedef __attribute__((ext_vector_type(4))) float  f32x4;

// fp32 -> bf16 bits, round-to-nearest-even (inputs are finite randn; no NaN path needed)
static __device__ __forceinline__ short f2bf(float f) {
    unsigned u = __builtin_bit_cast(unsigned, f);
    unsigned r = (u + 0x7fffu + ((u >> 16) & 1u)) >> 16;
    return (short)(unsigned short)r;
}

#define MFMA16(a, b, c)                                                         \
    __builtin_amdgcn_mfma_f32_16x16x32_bf16(__builtin_bit_cast(bf16x8, (a)),    \
                                            __builtin_bit_cast(bf16x8, (b)),    \
                                            (c), 0, 0, 0)

__global__ __launch_bounds__(256, 2) void attn_fwd(
    const float* __restrict__ Qg, const float* __restrict__ Kg,
    const float* __restrict__ Vg, float* __restrict__ Og)
{
    __shared__ short Kl[KVBLK][PAD];      // K tile, row-major [kv][c], bf16 bits
    __shared__ short Vt[HDIM][PAD];       // V tile, transposed [c][kv], bf16 bits
    __shared__ short Pl[4][32][PAD];      // per-wave P tile [q][kv], bf16 bits

    const int tid  = threadIdx.x;
    const int wave = tid >> 6;
    const int lane = tid & 63;
    const int llo  = lane & 15;
    const int lhi  = lane >> 4;

    const long base = (long)blockIdx.y * (T_SEQ * HDIM);
    const int  q0   = blockIdx.x * QBLK + wave * 32;

    // fold softmax scale (1/sqrt(64)) and log2(e) into Q so softmax is raw exp2
    const float qscale = 0.125f * 1.4426950408889634f;

    // ---- Q fragments: A[m=llo][k=lhi*8+i], 2 row-tiles x 2 K-chunks ----
    short8 aq[2][2];
    #pragma unroll
    for (int mi = 0; mi < 2; ++mi) {
        #pragma unroll
        for (int kc = 0; kc < 2; ++kc) {
            const f32x4* q4 = (const f32x4*)(Qg + base + (long)(q0 + mi * 16 + llo) * HDIM + kc * 32 + lhi * 8);
            f32x4 f0 = q4[0], f1 = q4[1];
            short8 a;
            #pragma unroll
            for (int i = 0; i < 4; ++i) { a[i] = f2bf(f0[i] * qscale); a[4 + i] = f2bf(f1[i] * qscale); }
            aq[mi][kc] = a;
        }
    }

    // ---- online-softmax state + O accumulators ----
    float mst[2][4], lst[2][4];
    f32x4 oacc[2][4];
    #pragma unroll
    for (int mi = 0; mi < 2; ++mi) {
        #pragma unroll
        for (int j = 0; j < 4; ++j) { mst[mi][j] = -1e30f; lst[mi][j] = 0.f; }
        #pragma unroll
        for (int ci = 0; ci < 4; ++ci) oacc[mi][ci] = f32x4{0.f, 0.f, 0.f, 0.f};
    }

    // staging map: thread t covers row t>>2, cols (t&3)*16 .. +15
    const int sr  = tid >> 2;
    const int scc = (tid & 3) * 16;
    const float* kp = Kg + base + (long)sr * HDIM + scc;
    const float* vp = Vg + base + (long)sr * HDIM + scc;

    for (int kv0 = 0; kv0 < T_SEQ; kv0 += KVBLK) {
        // ---- stage K (row-major) and V (transposed) as bf16 ----
        {
            const f32x4* k4 = (const f32x4*)(kp + (long)kv0 * HDIM);
            f32x4 a = k4[0], b = k4[1], c = k4[2], d = k4[3];
            short8 s0, s1;
            #pragma unroll
            for (int i = 0; i < 4; ++i) {
                s0[i] = f2bf(a[i]); s0[4 + i] = f2bf(b[i]);
                s1[i] = f2bf(c[i]); s1[4 + i] = f2bf(d[i]);
            }
            *(short8*)&Kl[sr][scc]     = s0;
            *(short8*)&Kl[sr][scc + 8] = s1;

            const f32x4* v4 = (const f32x4*)(vp + (long)kv0 * HDIM);
            f32x4 e = v4[0], f = v4[1], g = v4[2], h = v4[3];
            #pragma unroll
            for (int i = 0; i < 4; ++i) {
                Vt[scc + i     ][sr] = f2bf(e[i]);
                Vt[scc + 4 + i ][sr] = f2bf(f[i]);
                Vt[scc + 8 + i ][sr] = f2bf(g[i]);
                Vt[scc + 12 + i][sr] = f2bf(h[i]);
            }
        }
        __syncthreads();

        // ---- QK^T: S[q][kv], 2 mi x 4 ni tiles, K=64 in 2 chunks ----
        f32x4 sacc[2][4];
        #pragma unroll
        for (int mi = 0; mi < 2; ++mi)
            #pragma unroll
            for (int ni = 0; ni < 4; ++ni) sacc[mi][ni] = f32x4{0.f, 0.f, 0.f, 0.f};

        #pragma unroll
        for (int ni = 0; ni < 4; ++ni) {
            #pragma unroll
            for (int kc = 0; kc < 2; ++kc) {
                short8 bk = *(const short8*)&Kl[ni * 16 + llo][kc * 32 + lhi * 8];
                sacc[0][ni] = MFMA16(aq[0][kc], bk, sacc[0][ni]);
                sacc[1][ni] = MFMA16(aq[1][kc], bk, sacc[1][ni]);
            }
        }

        // ---- online softmax (fp32). Row q = mi*16 + lhi*4 + j spans {ni, llo}. ----
        #pragma unroll
        for (int mi = 0; mi < 2; ++mi) {
            float corr[4];
            #pragma unroll
            for (int j = 0; j < 4; ++j) {
                float t = fmaxf(fmaxf(sacc[mi][0][j], sacc[mi][1][j]),
                                fmaxf(sacc[mi][2][j], sacc[mi][3][j]));
                t = fmaxf(t, __shfl_xor(t, 1));
                t = fmaxf(t, __shfl_xor(t, 2));
                t = fmaxf(t, __shfl_xor(t, 4));
                t = fmaxf(t, __shfl_xor(t, 8));
                float mnew = fmaxf(mst[mi][j], t);
                corr[j] = exp2f(mst[mi][j] - mnew);
                mst[mi][j] = mnew;
            }
            float rs[4] = {0.f, 0.f, 0.f, 0.f};
            #pragma unroll
            for (int ni = 0; ni < 4; ++ni)
                #pragma unroll
                for (int j = 0; j < 4; ++j) {
                    float p = exp2f(sacc[mi][ni][j] - mst[mi][j]);
                    sacc[mi][ni][j] = p;
                    rs[j] += p;
                }
            #pragma unroll
            for (int j = 0; j < 4; ++j) {
                rs[j] += __shfl_xor(rs[j], 1);
                rs[j] += __shfl_xor(rs[j], 2);
                rs[j] += __shfl_xor(rs[j], 4);
                rs[j] += __shfl_xor(rs[j], 8);
                lst[mi][j] = lst[mi][j] * corr[j] + rs[j];
            }
            #pragma unroll
            for (int ci = 0; ci < 4; ++ci)
                #pragma unroll
                for (int j = 0; j < 4; ++j) oacc[mi][ci][j] *= corr[j];

            // P -> LDS in C/D layout position (fixes A-fragment layout mismatch)
            #pragma unroll
            for (int ni = 0; ni < 4; ++ni)
                #pragma unroll
                for (int j = 0; j < 4; ++j)
                    Pl[wave][mi * 16 + lhi * 4 + j][ni * 16 + llo] = f2bf(sacc[mi][ni][j]);
        }

        asm volatile("s_waitcnt lgkmcnt(0)" ::: "memory");

        // ---- PV: O[q][c] += P[q][s] * V[s][c], s=64 in 2 chunks ----
        #pragma unroll
        for (int sc2 = 0; sc2 < 2; ++sc2) {
            short8 ap0 = *(const short8*)&Pl[wave][llo     ][sc2 * 32 + lhi * 8];
            short8 ap1 = *(const short8*)&Pl[wave][16 + llo][sc2 * 32 + lhi * 8];
            #pragma unroll
            for (int ci = 0; ci < 4; ++ci) {
                short8 bv = *(const short8*)&Vt[ci * 16 + llo][sc2 * 32 + lhi * 8];
                oacc[0][ci] = MFMA16(ap0, bv, oacc[0][ci]);
                oacc[1][ci] = MFMA16(ap1, bv, oacc[1][ci]);
            }
        }
        __syncthreads();
    }

    // ---- epilogue: O = oacc / l ----
    #pragma unroll
    for (int mi = 0; mi < 2; ++mi)
        #pragma unroll
        for (int j = 0; j < 4; ++j) {
            float inv = 1.f / lst[mi][j];
            float* op = Og + base + (long)(q0 + mi * 16 + lhi * 4 + j) * HDIM + llo;
            #pragma unroll
            for (int ci = 0; ci < 4; ++ci) op[ci * 16] = oacc[mi][ci][j] * inv;
        }
}

extern "C" void kernel_launch(void* const* d_in, const int* in_sizes, int n_in,
                              void* d_out, int out_size, void* d_ws, size_t ws_size,
                              hipStream_t stream) {
    const float* Q = (const float*)d_in[0];
    const float* K = (const float*)d_in[1];
    const float* V = (const float*)d_in[2];
    float* O = (float*)d_out;
    const int bh = in_sizes[0] / (T_SEQ * HDIM);   // B*H = 16
    dim3 grid(T_SEQ / QBLK, bh);
    attn_fwd<<<grid, 256, 0, stream>>>(Q, K, V, O);
}

// Round 3
// 215.969 us; speedup vs baseline: 1.5044x; 1.5044x over previous
//
#include <hip/hip_runtime.h>
#include <hip/hip_bf16.h>

#define T_SEQ 4096
#define HDIM  64
#define KVBLK 64
#define WAVES 4
#define QBLK  (32 * WAVES)   // 128 q-rows per block, 32 per wave

typedef __attribute__((ext_vector_type(8)))  short    short8;
typedef __attribute__((ext_vector_type(8)))  __bf16   bf16x8;
typedef __attribute__((ext_vector_type(4)))  float    f32x4;
typedef __attribute__((ext_vector_type(16))) float    f32x16;
typedef __attribute__((ext_vector_type(2)))  unsigned uint2v;
typedef __attribute__((ext_vector_type(4)))  unsigned uint4v;

static __device__ __forceinline__ unsigned cvtpk(float lo, float hi) {
    unsigned r;
    asm("v_cvt_pk_bf16_f32 %0, %1, %2" : "=v"(r) : "v"(lo), "v"(hi));
    return r;
}

#define MFMA32(a, b, c)                                                        \
    __builtin_amdgcn_mfma_f32_32x32x16_bf16(__builtin_bit_cast(bf16x8, (a)),   \
                                            __builtin_bit_cast(bf16x8, (b)),   \
                                            (c), 0, 0, 0)

// LDS tiles: rows of 64 bf16 (128 B). XOR swizzle at 16B-slot granularity:
// slot' = slot ^ (row & 7)  -> GEMM-style 32-row column reads conflict-free.
__global__ __launch_bounds__(256, 2) void attn_fwd(
    const float* __restrict__ Qg, const float* __restrict__ Kg,
    const float* __restrict__ Vg, float* __restrict__ Og)
{
    __shared__ __align__(16) short Kl[KVBLK * HDIM];  // [kv][c], swizzled
    __shared__ __align__(16) short Vt[HDIM * KVBLK];  // [c][kv], swizzled

    const int tid  = threadIdx.x;
    const int wave = tid >> 6;
    const int lane = tid & 63;
    const int n    = lane & 31;   // q (QK^T) / c (PV) / LDS row selector
    const int hi   = lane >> 5;
    const int n7   = n & 7;

    const long base = (long)blockIdx.y * (T_SEQ * HDIM);
    const int  q0   = blockIdx.x * QBLK + wave * 32;

    // fold 1/sqrt(64) and log2(e) into Q -> softmax uses raw exp2
    const float qscale = 0.125f * 1.4426950408889634f;

    // ---- Q as B-fragments: B[k=c][n=q], q = q0+n, c = kc*16 + hi*8 + i ----
    bf16x8 qf[4];
    #pragma unroll
    for (int kc = 0; kc < 4; ++kc) {
        const f32x4* qp = (const f32x4*)(Qg + base + (long)(q0 + n) * HDIM + kc * 16 + hi * 8);
        f32x4 a = qp[0], b = qp[1];
        uint4v u;
        u[0] = cvtpk(a[0] * qscale, a[1] * qscale);
        u[1] = cvtpk(a[2] * qscale, a[3] * qscale);
        u[2] = cvtpk(b[0] * qscale, b[1] * qscale);
        u[3] = cvtpk(b[2] * qscale, b[3] * qscale);
        qf[kc] = __builtin_bit_cast(bf16x8, u);
    }

    float mrun = -1e30f, lrun = 0.f;
    f32x16 oacc[2];
    #pragma unroll
    for (int nt = 0; nt < 2; ++nt)
        #pragma unroll
        for (int r = 0; r < 16; ++r) oacc[nt][r] = 0.f;

    // ---- staging maps ----
    // K: thread t -> row sr = t>>2, slots {t&3, (t&3)+4} (8 bf16 each)
    const int sr = tid >> 2;
    const int ss = tid & 3;
    const float* kp = Kg + base + (long)sr * HDIM;
    // V transpose: thread t -> c in [4cb,4cb+4), kv in [4kb,4kb+4)
    const int cb = (tid & 15) * 4;
    const int kb = tid >> 4;  // 0..15
    const float* vp = Vg + base + (long)(kb * 4) * HDIM + cb;

    for (int kv0 = 0; kv0 < T_SEQ; kv0 += KVBLK) {
        // ---- stage K (row-major, swizzled) ----
        #pragma unroll
        for (int u = 0; u < 2; ++u) {
            const int s = ss + u * 4;
            const f32x4* src = (const f32x4*)(kp + (long)kv0 * HDIM + s * 8);
            f32x4 a = src[0], b = src[1];
            uint4v w;
            w[0] = cvtpk(a[0], a[1]); w[1] = cvtpk(a[2], a[3]);
            w[2] = cvtpk(b[0], b[1]); w[3] = cvtpk(b[2], b[3]);
            *(uint4v*)&Kl[sr * 64 + ((s ^ (sr & 7)) * 8)] = w;
        }
        // ---- stage V^T (4x4 block transpose, b64 pair writes, swizzled) ----
        {
            const float* vs = vp + (long)kv0 * HDIM;
            f32x4 r0 = *(const f32x4*)(vs);
            f32x4 r1 = *(const f32x4*)(vs + HDIM);
            f32x4 r2 = *(const f32x4*)(vs + 2 * HDIM);
            f32x4 r3 = *(const f32x4*)(vs + 3 * HDIM);
            #pragma unroll
            for (int i = 0; i < 4; ++i) {
                uint2v w;
                w[0] = cvtpk(r0[i], r1[i]);   // kv 4kb, 4kb+1
                w[1] = cvtpk(r2[i], r3[i]);   // kv 4kb+2, 4kb+3
                const int row = cb + i;       // c
                *(uint2v*)&Vt[row * 64 + (((kb >> 1) ^ (row & 7)) * 8) + (kb & 1) * 4] = w;
            }
        }
        __syncthreads();

        // ---- swapped QK^T: S^T[kv][q] = K · Q^T ----
        f32x16 sacc[2];
        #pragma unroll
        for (int mt = 0; mt < 2; ++mt)
            #pragma unroll
            for (int r = 0; r < 16; ++r) sacc[mt][r] = 0.f;
        #pragma unroll
        for (int mt = 0; mt < 2; ++mt) {
            #pragma unroll
            for (int kc = 0; kc < 4; ++kc) {
                short8 ka = *(const short8*)&Kl[(mt * 32 + n) * 64 + (((2 * kc + hi) ^ n7) * 8)];
                sacc[mt] = MFMA32(ka, qf[kc], sacc[mt]);
            }
        }

        // ---- in-register online softmax (lane tracks row q = q0 + (lane&31)) ----
        float pm = sacc[0][0];
        #pragma unroll
        for (int r = 1; r < 16; ++r) pm = fmaxf(pm, sacc[0][r]);
        #pragma unroll
        for (int r = 0; r < 16; ++r) pm = fmaxf(pm, sacc[1][r]);
        pm = fmaxf(pm, __shfl_xor(pm, 32));
        const float mnew = fmaxf(mrun, pm);
        const float corr = exp2f(mrun - mnew);
        mrun = mnew;

        float rsum = 0.f;
        #pragma unroll
        for (int mt = 0; mt < 2; ++mt)
            #pragma unroll
            for (int r = 0; r < 16; ++r) {
                float p = exp2f(sacc[mt][r] - mnew);
                sacc[mt][r] = p;
                rsum += p;
            }
        rsum += __shfl_xor(rsum, 32);
        lrun = lrun * corr + rsum;

        // ---- rescale O: row of oacc[*][r] is q' = (r&3)+8(r>>2)+4hi, NOT lane's q.
        // corr is parity-symmetric (max was reduced across the lane pair), so
        // lane qoff in [0,32) holds the right factor for row qoff.
        #pragma unroll
        for (int r = 0; r < 16; ++r) {
            const int qoff = (r & 3) + 8 * (r >> 2) + 4 * hi;
            const float cR = __shfl(corr, qoff);
            oacc[0][r] *= cR;
            oacc[1][r] *= cR;
        }

        // ---- pack P -> A-fragments in registers ----
        // lane holds sacc[mt][4s+j] = P[q][kv = 32mt + 8s + 4hi + j]
        // A-frag slot ks=2mt+sl, elem i=4b+j needs P[q'][kv=16ks+8hi_c+4b+j]
        //   -> source lane parity = b, source reg index = 8sl + 4hi_c + j
        bf16x8 pa[4];
        #pragma unroll
        for (int mt = 0; mt < 2; ++mt) {
            #pragma unroll
            for (int ksl = 0; ksl < 2; ++ksl) {
                uint4v W;
                #pragma unroll
                for (int t = 0; t < 2; ++t) {
                    unsigned X = cvtpk(sacc[mt][8 * ksl + 2 * t],     sacc[mt][8 * ksl + 2 * t + 1]);
                    unsigned Y = cvtpk(sacc[mt][8 * ksl + 4 + 2 * t], sacc[mt][8 * ksl + 4 + 2 * t + 1]);
                    unsigned sx = __shfl_xor(X, 32);
                    unsigned sy = __shfl_xor(Y, 32);
                    W[t]     = hi ? sy : X;   // low half-wave: own X; high: partner's Y
                    W[2 + t] = hi ? Y  : sx;  // low: partner's X; high: own Y
                }
                pa[mt * 2 + ksl] = __builtin_bit_cast(bf16x8, W);
            }
        }

        // ---- PV: O[q][c] += P·V, A=P frags, B=V^T rows from LDS ----
        #pragma unroll
        for (int nt = 0; nt < 2; ++nt) {
            #pragma unroll
            for (int ks = 0; ks < 4; ++ks) {
                short8 vb = *(const short8*)&Vt[(nt * 32 + n) * 64 + (((2 * ks + hi) ^ n7) * 8)];
                oacc[nt] = MFMA32(pa[ks], vb, oacc[nt]);
            }
        }
        __syncthreads();
    }

    // ---- epilogue: O = oacc / l ; lane's O rows are q' = (r&3)+8(r>>2)+4hi ----
    const float linv = 1.f / lrun;
    #pragma unroll
    for (int r = 0; r < 16; ++r) {
        const int qoff = (r & 3) + 8 * (r >> 2) + 4 * hi;
        const float li = __shfl(linv, qoff);
        float* op = Og + base + (long)(q0 + qoff) * HDIM + n;
        op[0]  = oacc[0][r] * li;
        op[32] = oacc[1][r] * li;
    }
}

extern "C" void kernel_launch(void* const* d_in, const int* in_sizes, int n_in,
                              void* d_out, int out_size, void* d_ws, size_t ws_size,
                              hipStream_t stream) {
    const float* Q = (const float*)d_in[0];
    const float* K = (const float*)d_in[1];
    const float* V = (const float*)d_in[2];
    float* O = (float*)d_out;
    const int bh = in_sizes[0] / (T_SEQ * HDIM);   // 16
    dim3 grid(T_SEQ / QBLK, bh);
    attn_fwd<<<grid, 256, 0, stream>>>(Q, K, V, O);
}

// Round 4
// 149.060 us; speedup vs baseline: 2.1796x; 1.4489x over previous
//
#include <hip/hip_runtime.h>
#include <hip/hip_bf16.h>

#define T_SEQ 4096
#define HDIM  64
#define KVBLK 64
#define NT    (T_SEQ / KVBLK)
#define WAVES 4
#define QBLK  (32 * WAVES)   // 128 q-rows per block, 32 per wave

typedef __attribute__((ext_vector_type(8)))  short    short8;
typedef __attribute__((ext_vector_type(8)))  __bf16   bf16x8;
typedef __attribute__((ext_vector_type(4)))  float    f32x4;
typedef __attribute__((ext_vector_type(16))) float    f32x16;
typedef __attribute__((ext_vector_type(2)))  unsigned uint2v;
typedef __attribute__((ext_vector_type(4)))  unsigned uint4v;

static __device__ __forceinline__ unsigned cvtpk(float lo, float hi) {
    unsigned r;
    asm("v_cvt_pk_bf16_f32 %0, %1, %2" : "=v"(r) : "v"(lo), "v"(hi));
    return r;
}

#define MFMA32(a, b, c)                                                        \
    __builtin_amdgcn_mfma_f32_32x32x16_bf16(__builtin_bit_cast(bf16x8, (a)),   \
                                            __builtin_bit_cast(bf16x8, (b)),   \
                                            (c), 0, 0, 0)

static __device__ __forceinline__ float max16(const f32x16& v) {
    float a = fmaxf(fmaxf(v[0], v[1]), fmaxf(v[2], v[3]));
    float b = fmaxf(fmaxf(v[4], v[5]), fmaxf(v[6], v[7]));
    float c = fmaxf(fmaxf(v[8], v[9]), fmaxf(v[10], v[11]));
    float d = fmaxf(fmaxf(v[12], v[13]), fmaxf(v[14], v[15]));
    return fmaxf(fmaxf(a, b), fmaxf(c, d));
}

// LDS rows = 64 bf16 (128 B). XOR swizzle at 16B-slot granularity:
// slot' = slot ^ (row & 7); writes AND reads both apply it.
__global__ __launch_bounds__(256, 2) void attn_fwd(
    const float* __restrict__ Qg, const float* __restrict__ Kg,
    const float* __restrict__ Vg, float* __restrict__ Og)
{
    __shared__ __align__(16) short Kl[2][KVBLK * HDIM];  // [buf][kv][c]
    __shared__ __align__(16) short Vt[2][HDIM * KVBLK];  // [buf][c][kv]

    const int tid  = threadIdx.x;
    const int wave = tid >> 6;
    const int lane = tid & 63;
    const int n    = lane & 31;
    const int hi   = lane >> 5;
    const int n7   = n & 7;

    const long base = (long)blockIdx.y * (T_SEQ * HDIM);
    const int  q0   = blockIdx.x * QBLK + wave * 32;

    const float qscale = 0.125f * 1.4426950408889634f;  // 1/sqrt(64) * log2(e)

    // ---- Q as B-fragments: B[k=c][n=q], q=q0+n, c=kc*16+hi*8+i ----
    bf16x8 qf[4];
    #pragma unroll
    for (int kc = 0; kc < 4; ++kc) {
        const f32x4* qp = (const f32x4*)(Qg + base + (long)(q0 + n) * HDIM + kc * 16 + hi * 8);
        f32x4 a = qp[0], b = qp[1];
        uint4v u;
        u[0] = cvtpk(a[0] * qscale, a[1] * qscale);
        u[1] = cvtpk(a[2] * qscale, a[3] * qscale);
        u[2] = cvtpk(b[0] * qscale, b[1] * qscale);
        u[3] = cvtpk(b[2] * qscale, b[3] * qscale);
        qf[kc] = __builtin_bit_cast(bf16x8, u);
    }

    float mrun = -1e30f, lrun = 0.f;
    f32x16 oacc[2];
    #pragma unroll
    for (int nt = 0; nt < 2; ++nt)
        #pragma unroll
        for (int r = 0; r < 16; ++r) oacc[nt][r] = 0.f;

    // ---- staging maps (conflict-free write groups) ----
    // K: thread t -> rows {t>>3, t>>3+32}, slot t&7 (8 bf16 = 32B global read)
    const int krow  = tid >> 3;   // 0..31
    const int kslot = tid & 7;
    // V: thread t -> kv rows 4*(t&15)..+3, c cols 4*(t>>4)..+3 (4x4 transpose)
    const int vkb = tid & 15;
    const int vcb = tid >> 4;     // 0..15

    f32x4 kr[2][2], vr[4];

    auto LOADT = [&](int t) {
        const float* kp = Kg + base + (long)(t * KVBLK + krow) * HDIM + kslot * 8;
        kr[0][0] = ((const f32x4*)kp)[0];
        kr[0][1] = ((const f32x4*)kp)[1];
        const float* kp1 = kp + 32 * HDIM;
        kr[1][0] = ((const f32x4*)kp1)[0];
        kr[1][1] = ((const f32x4*)kp1)[1];
        const float* vp = Vg + base + (long)(t * KVBLK + vkb * 4) * HDIM + vcb * 4;
        #pragma unroll
        for (int j = 0; j < 4; ++j) vr[j] = ((const f32x4*)(vp + j * HDIM))[0];
    };

    auto STORET = [&](int b) {
        #pragma unroll
        for (int p = 0; p < 2; ++p) {
            const int row = krow + 32 * p;
            uint4v w;
            w[0] = cvtpk(kr[p][0][0], kr[p][0][1]);
            w[1] = cvtpk(kr[p][0][2], kr[p][0][3]);
            w[2] = cvtpk(kr[p][1][0], kr[p][1][1]);
            w[3] = cvtpk(kr[p][1][2], kr[p][1][3]);
            *(uint4v*)&Kl[b][row * 64 + ((kslot ^ (row & 7)) * 8)] = w;
        }
        #pragma unroll
        for (int i = 0; i < 4; ++i) {
            const int row = vcb * 4 + i;   // c
            uint2v w;
            w[0] = cvtpk(vr[0][i], vr[1][i]);   // kv 4vkb, 4vkb+1
            w[1] = cvtpk(vr[2][i], vr[3][i]);   // kv 4vkb+2, 4vkb+3
            *(uint2v*)&Vt[b][row * 64 + (((vkb >> 1) ^ (row & 7)) * 8) + (vkb & 1) * 4] = w;
        }
    };

    // ---- prologue: fill buf0, prefetch tile 1 ----
    LOADT(0);
    STORET(0);
    LOADT(1);
    __syncthreads();

    for (int t = 0; t < NT; ++t) {
        const int cur = t & 1;
        // write next tile's LDS (regs hold tile t+1), then prefetch t+2
        if (t + 1 < NT) {
            STORET(cur ^ 1);
            if (t + 2 < NT) LOADT(t + 2);
        }

        // ---- swapped QK^T: S^T[kv][q] ----
        f32x16 sacc[2];
        #pragma unroll
        for (int mt = 0; mt < 2; ++mt)
            #pragma unroll
            for (int r = 0; r < 16; ++r) sacc[mt][r] = 0.f;
        __builtin_amdgcn_s_setprio(1);
        #pragma unroll
        for (int mt = 0; mt < 2; ++mt) {
            #pragma unroll
            for (int kc = 0; kc < 4; ++kc) {
                short8 ka = *(const short8*)&Kl[cur][(mt * 32 + n) * 64 + (((2 * kc + hi) ^ n7) * 8)];
                sacc[mt] = MFMA32(ka, qf[kc], sacc[mt]);
            }
        }
        __builtin_amdgcn_s_setprio(0);

        // ---- online softmax with defer-max (lane's row q = q0 + n) ----
        float pm = fmaxf(max16(sacc[0]), max16(sacc[1]));
        pm = fmaxf(pm, __shfl_xor(pm, 32));

        if (!__all(pm - mrun <= 8.f)) {
            const float mnew = fmaxf(mrun, pm);
            const float corr = exp2f(mrun - mnew);
            mrun = mnew;
            lrun *= corr;
            // oacc row r is q' = (r&3)+8(r>>2)+4hi; corr is pair-symmetric
            #pragma unroll
            for (int r = 0; r < 16; ++r) {
                const int qoff = (r & 3) + 8 * (r >> 2) + 4 * hi;
                const float cR = __shfl(corr, qoff);
                oacc[0][r] *= cR;
                oacc[1][r] *= cR;
            }
        }

        float rs[4] = {0.f, 0.f, 0.f, 0.f};
        #pragma unroll
        for (int mt = 0; mt < 2; ++mt)
            #pragma unroll
            for (int r = 0; r < 16; ++r) {
                float p = exp2f(sacc[mt][r] - mrun);
                sacc[mt][r] = p;
                rs[r & 3] += p;
            }
        float rsum = (rs[0] + rs[1]) + (rs[2] + rs[3]);
        rsum += __shfl_xor(rsum, 32);
        lrun += rsum;

        // ---- pack P -> A-fragments (half-wave exchange) ----
        bf16x8 pa[4];
        #pragma unroll
        for (int mt = 0; mt < 2; ++mt) {
            #pragma unroll
            for (int ksl = 0; ksl < 2; ++ksl) {
                uint4v W;
                #pragma unroll
                for (int tt = 0; tt < 2; ++tt) {
                    unsigned X = cvtpk(sacc[mt][8 * ksl + 2 * tt],     sacc[mt][8 * ksl + 2 * tt + 1]);
                    unsigned Y = cvtpk(sacc[mt][8 * ksl + 4 + 2 * tt], sacc[mt][8 * ksl + 4 + 2 * tt + 1]);
                    unsigned sx = __shfl_xor(X, 32);
                    unsigned sy = __shfl_xor(Y, 32);
                    W[tt]     = hi ? sy : X;
                    W[2 + tt] = hi ? Y  : sx;
                }
                pa[mt * 2 + ksl] = __builtin_bit_cast(bf16x8, W);
            }
        }

        // ---- PV: O += P·V ----
        __builtin_amdgcn_s_setprio(1);
        #pragma unroll
        for (int nt = 0; nt < 2; ++nt) {
            #pragma unroll
            for (int ks = 0; ks < 4; ++ks) {
                short8 vb = *(const short8*)&Vt[cur][(nt * 32 + n) * 64 + (((2 * ks + hi) ^ n7) * 8)];
                oacc[nt] = MFMA32(pa[ks], vb, oacc[nt]);
            }
        }
        __builtin_amdgcn_s_setprio(0);

        __syncthreads();
    }

    // ---- epilogue ----
    const float linv = 1.f / lrun;
    #pragma unroll
    for (int r = 0; r < 16; ++r) {
        const int qoff = (r & 3) + 8 * (r >> 2) + 4 * hi;
        const float li = __shfl(linv, qoff);
        float* op = Og + base + (long)(q0 + qoff) * HDIM + n;
        op[0]  = oacc[0][r] * li;
        op[32] = oacc[1][r] * li;
    }
}

extern "C" void kernel_launch(void* const* d_in, const int* in_sizes, int n_in,
                              void* d_out, int out_size, void* d_ws, size_t ws_size,
                              hipStream_t stream) {
    const float* Q = (const float*)d_in[0];
    const float* K = (const float*)d_in[1];
    const float* V = (const float*)d_in[2];
    float* O = (float*)d_out;
    const int bh = in_sizes[0] / (T_SEQ * HDIM);   // 16
    dim3 grid(T_SEQ / QBLK, bh);
    attn_fwd<<<grid, 256, 0, stream>>>(Q, K, V, O);
}

// Round 5
// 127.840 us; speedup vs baseline: 2.5414x; 1.1660x over previous
//
#include <hip/hip_runtime.h>
#include <hip/hip_bf16.h>

#define T_SEQ 4096
#define HDIM  64
#define KVBLK 64
#define NT    (T_SEQ / KVBLK)
#define WAVES 4
#define QBLK  (32 * WAVES)   // 128 q-rows per block, 32 per wave

typedef __attribute__((ext_vector_type(8)))  short    short8;
typedef __attribute__((ext_vector_type(8)))  __bf16   bf16x8;
typedef __attribute__((ext_vector_type(4)))  float    f32x4;
typedef __attribute__((ext_vector_type(16))) float    f32x16;
typedef __attribute__((ext_vector_type(2)))  unsigned uint2v;
typedef __attribute__((ext_vector_type(4)))  unsigned uint4v;

static __device__ __forceinline__ unsigned cvtpk(float lo, float hi) {
    unsigned r;
    asm("v_cvt_pk_bf16_f32 %0, %1, %2" : "=v"(r) : "v"(lo), "v"(hi));
    return r;
}

#define MFMA32(a, b, c)                                                        \
    __builtin_amdgcn_mfma_f32_32x32x16_bf16(__builtin_bit_cast(bf16x8, (a)),   \
                                            __builtin_bit_cast(bf16x8, (b)),   \
                                            (c), 0, 0, 0)

static __device__ __forceinline__ float max16(const f32x16& v) {
    float a = fmaxf(fmaxf(v[0], v[1]), fmaxf(v[2], v[3]));
    float b = fmaxf(fmaxf(v[4], v[5]), fmaxf(v[6], v[7]));
    float c = fmaxf(fmaxf(v[8], v[9]), fmaxf(v[10], v[11]));
    float d = fmaxf(fmaxf(v[12], v[13]), fmaxf(v[14], v[15]));
    return fmaxf(fmaxf(a, b), fmaxf(c, d));
}

// ============================ pre-pass kernels ============================
// K: fp32 [bh][t][c] -> bf16 [bh][t][c] (plain cast, vectorized)
__global__ __launch_bounds__(256) void cvt_k(const float* __restrict__ K,
                                             short* __restrict__ Kb) {
    const long i = (long)blockIdx.x * 256 + threadIdx.x;   // 8 elems each
    const f32x4* s = (const f32x4*)(K + i * 8);
    f32x4 a = s[0], b = s[1];
    uint4v w;
    w[0] = cvtpk(a[0], a[1]); w[1] = cvtpk(a[2], a[3]);
    w[2] = cvtpk(b[0], b[1]); w[3] = cvtpk(b[2], b[3]);
    *(uint4v*)(Kb + i * 8) = w;
}

// V: fp32 [bh][t][c] -> bf16 transposed [bh][c][t] via LDS 64x64 tile
__global__ __launch_bounds__(256) void cvt_vt(const float* __restrict__ V,
                                              short* __restrict__ Vtb) {
    __shared__ float Vl[64][65];
    const int tid = threadIdx.x;
    const int bh  = blockIdx.y;
    const int t0  = blockIdx.x * 64;
    const float* src = V + ((long)bh * T_SEQ + t0) * HDIM;
    #pragma unroll
    for (int k = 0; k < 4; ++k) {
        const int idx = k * 256 + tid;          // chunk: row=idx>>4, col4=(idx&15)*4
        const int r = idx >> 4, c4 = (idx & 15) * 4;
        f32x4 v = *(const f32x4*)(src + r * HDIM + c4);
        Vl[r][c4] = v[0]; Vl[r][c4 + 1] = v[1]; Vl[r][c4 + 2] = v[2]; Vl[r][c4 + 3] = v[3];
    }
    __syncthreads();
    #pragma unroll
    for (int k = 0; k < 2; ++k) {
        const int o = k * 256 + tid;            // out chunk: c=o>>3, 8 t-values
        const int c = o >> 3, ts = (o & 7) * 8;
        uint4v w;
        w[0] = cvtpk(Vl[ts + 0][c], Vl[ts + 1][c]);
        w[1] = cvtpk(Vl[ts + 2][c], Vl[ts + 3][c]);
        w[2] = cvtpk(Vl[ts + 4][c], Vl[ts + 5][c]);
        w[3] = cvtpk(Vl[ts + 6][c], Vl[ts + 7][c]);
        *(uint4v*)(Vtb + ((long)bh * HDIM + c) * T_SEQ + t0 + ts) = w;
    }
}

// ============================ main kernel (bf16 K/V via global_load_lds) ====
// LDS rows = 64 bf16 (128 B), LINEAR layout; swizzle slot'=slot^(row&7) is
// pre-applied on the per-lane GLOBAL source address (m173 pattern); reads
// apply the same XOR.
__global__ __launch_bounds__(256, 2) void attn_fwd2(
    const float* __restrict__ Qg, const short* __restrict__ Kb,
    const short* __restrict__ Vtb, float* __restrict__ Og)
{
    __shared__ __align__(16) short Kl[2][KVBLK * HDIM];
    __shared__ __align__(16) short Vt[2][HDIM * KVBLK];

    const int tid  = threadIdx.x;
    const int wave = tid >> 6;
    const int lane = tid & 63;
    const int n    = lane & 31;
    const int hi   = lane >> 5;
    const int n7   = n & 7;

    const int  bh   = blockIdx.y;
    const long base = (long)bh * (T_SEQ * HDIM);
    const int  q0   = blockIdx.x * QBLK + wave * 32;

    const float qscale = 0.125f * 1.4426950408889634f;  // 1/sqrt(64) * log2(e)

    // ---- staging source pointers (per lane, swizzle folded into global addr)
    // lane l covers local row l>>3, LDS slot l&7; content slot = (l&7)^(l>>3)
    const int l8 = lane >> 3, l7 = lane & 7;
    const int swz8 = (l7 ^ l8) * 8;                       // elements
    const short* kg0 = Kb + (long)bh * T_SEQ * HDIM + (16 * wave + l8) * HDIM + swz8;
    const short* vg0 = Vtb + ((long)bh * HDIM + 16 * wave + l8) * T_SEQ + swz8;

    auto STAGE = [&](int b, int t) {
        #pragma unroll
        for (int i = 0; i < 2; ++i) {
            __builtin_amdgcn_global_load_lds(
                (const unsigned*)(kg0 + (long)t * (KVBLK * HDIM) + i * 512),
                (unsigned*)&Kl[b][(16 * wave + 8 * i) * 64], 16, 0, 0);
            __builtin_amdgcn_global_load_lds(
                (const unsigned*)(vg0 + (long)t * KVBLK + (long)i * 8 * T_SEQ),
                (unsigned*)&Vt[b][(16 * wave + 8 * i) * 64], 16, 0, 0);
        }
    };

    STAGE(0, 0);

    // ---- Q as B-fragments: B[k=c][n=q], q=q0+n, c=kc*16+hi*8+i ----
    bf16x8 qf[4];
    #pragma unroll
    for (int kc = 0; kc < 4; ++kc) {
        const f32x4* qp = (const f32x4*)(Qg + base + (long)(q0 + n) * HDIM + kc * 16 + hi * 8);
        f32x4 a = qp[0], b = qp[1];
        uint4v u;
        u[0] = cvtpk(a[0] * qscale, a[1] * qscale);
        u[1] = cvtpk(a[2] * qscale, a[3] * qscale);
        u[2] = cvtpk(b[0] * qscale, b[1] * qscale);
        u[3] = cvtpk(b[2] * qscale, b[3] * qscale);
        qf[kc] = __builtin_bit_cast(bf16x8, u);
    }

    float mrun = -1e30f, lrun = 0.f;
    f32x16 oacc[2];
    #pragma unroll
    for (int nt = 0; nt < 2; ++nt)
        #pragma unroll
        for (int r = 0; r < 16; ++r) oacc[nt][r] = 0.f;

    __syncthreads();   // drains vmcnt(0): tile 0 staged

    for (int t = 0; t < NT; ++t) {
        const int cur = t & 1;
        if (t + 1 < NT) STAGE(cur ^ 1, t + 1);

        // ---- swapped QK^T: S^T[kv][q] ----
        f32x16 sacc[2];
        #pragma unroll
        for (int mt = 0; mt < 2; ++mt)
            #pragma unroll
            for (int r = 0; r < 16; ++r) sacc[mt][r] = 0.f;
        __builtin_amdgcn_s_setprio(1);
        #pragma unroll
        for (int mt = 0; mt < 2; ++mt) {
            #pragma unroll
            for (int kc = 0; kc < 4; ++kc) {
                short8 ka = *(const short8*)&Kl[cur][(mt * 32 + n) * 64 + (((2 * kc + hi) ^ n7) * 8)];
                sacc[mt] = MFMA32(ka, qf[kc], sacc[mt]);
            }
        }
        __builtin_amdgcn_s_setprio(0);

        // ---- online softmax with defer-max (lane's row q = q0 + n) ----
        float pm = fmaxf(max16(sacc[0]), max16(sacc[1]));
        pm = fmaxf(pm, __shfl_xor(pm, 32));

        if (!__all(pm - mrun <= 8.f)) {
            const float mnew = fmaxf(mrun, pm);
            const float corr = __builtin_amdgcn_exp2f(mrun - mnew);
            mrun = mnew;
            lrun *= corr;
            #pragma unroll
            for (int r = 0; r < 16; ++r) {
                const int qoff = (r & 3) + 8 * (r >> 2) + 4 * hi;
                const float cR = __shfl(corr, qoff);
                oacc[0][r] *= cR;
                oacc[1][r] *= cR;
            }
        }

        float rs[4] = {0.f, 0.f, 0.f, 0.f};
        #pragma unroll
        for (int mt = 0; mt < 2; ++mt)
            #pragma unroll
            for (int r = 0; r < 16; ++r) {
                float p = __builtin_amdgcn_exp2f(sacc[mt][r] - mrun);
                sacc[mt][r] = p;
                rs[r & 3] += p;
            }
        float rsum = (rs[0] + rs[1]) + (rs[2] + rs[3]);
        rsum += __shfl_xor(rsum, 32);
        lrun += rsum;

        // ---- pack P -> A-fragments (verified half-wave exchange) ----
        bf16x8 pa[4];
        #pragma unroll
        for (int mt = 0; mt < 2; ++mt) {
            #pragma unroll
            for (int ksl = 0; ksl < 2; ++ksl) {
                uint4v W;
                #pragma unroll
                for (int tt = 0; tt < 2; ++tt) {
                    unsigned X = cvtpk(sacc[mt][8 * ksl + 2 * tt],     sacc[mt][8 * ksl + 2 * tt + 1]);
                    unsigned Y = cvtpk(sacc[mt][8 * ksl + 4 + 2 * tt], sacc[mt][8 * ksl + 4 + 2 * tt + 1]);
                    unsigned sx = __shfl_xor(X, 32);
                    unsigned sy = __shfl_xor(Y, 32);
                    W[tt]     = hi ? sy : X;
                    W[2 + tt] = hi ? Y  : sx;
                }
                pa[mt * 2 + ksl] = __builtin_bit_cast(bf16x8, W);
            }
        }

        // ---- PV: O += P·V ----
        __builtin_amdgcn_s_setprio(1);
        #pragma unroll
        for (int nt = 0; nt < 2; ++nt) {
            #pragma unroll
            for (int ks = 0; ks < 4; ++ks) {
                short8 vb = *(const short8*)&Vt[cur][(nt * 32 + n) * 64 + (((2 * ks + hi) ^ n7) * 8)];
                oacc[nt] = MFMA32(pa[ks], vb, oacc[nt]);
            }
        }
        __builtin_amdgcn_s_setprio(0);

        __syncthreads();   // drains vmcnt(0) (next tile staged) + joins waves
    }

    const float linv = 1.f / lrun;
    #pragma unroll
    for (int r = 0; r < 16; ++r) {
        const int qoff = (r & 3) + 8 * (r >> 2) + 4 * hi;
        const float li = __shfl(linv, qoff);
        float* op = Og + base + (long)(q0 + qoff) * HDIM + n;
        op[0]  = oacc[0][r] * li;
        op[32] = oacc[1][r] * li;
    }
}

// ============================ fallback (round-4 verified, fp32 reg-staging) ==
__global__ __launch_bounds__(256, 2) void attn_fwd_fb(
    const float* __restrict__ Qg, const float* __restrict__ Kg,
    const float* __restrict__ Vg, float* __restrict__ Og)
{
    __shared__ __align__(16) short Kl[2][KVBLK * HDIM];
    __shared__ __align__(16) short Vt[2][HDIM * KVBLK];

    const int tid  = threadIdx.x;
    const int wave = tid >> 6;
    const int lane = tid & 63;
    const int n    = lane & 31;
    const int hi   = lane >> 5;
    const int n7   = n & 7;

    const long base = (long)blockIdx.y * (T_SEQ * HDIM);
    const int  q0   = blockIdx.x * QBLK + wave * 32;
    const float qscale = 0.125f * 1.4426950408889634f;

    bf16x8 qf[4];
    #pragma unroll
    for (int kc = 0; kc < 4; ++kc) {
        const f32x4* qp = (const f32x4*)(Qg + base + (long)(q0 + n) * HDIM + kc * 16 + hi * 8);
        f32x4 a = qp[0], b = qp[1];
        uint4v u;
        u[0] = cvtpk(a[0] * qscale, a[1] * qscale);
        u[1] = cvtpk(a[2] * qscale, a[3] * qscale);
        u[2] = cvtpk(b[0] * qscale, b[1] * qscale);
        u[3] = cvtpk(b[2] * qscale, b[3] * qscale);
        qf[kc] = __builtin_bit_cast(bf16x8, u);
    }

    float mrun = -1e30f, lrun = 0.f;
    f32x16 oacc[2];
    #pragma unroll
    for (int nt = 0; nt < 2; ++nt)
        #pragma unroll
        for (int r = 0; r < 16; ++r) oacc[nt][r] = 0.f;

    const int krow  = tid >> 3;
    const int kslot = tid & 7;
    const int vkb = tid & 15;
    const int vcb = tid >> 4;

    f32x4 kr[2][2], vr[4];

    auto LOADT = [&](int t) {
        const float* kp = Kg + base + (long)(t * KVBLK + krow) * HDIM + kslot * 8;
        kr[0][0] = ((const f32x4*)kp)[0];
        kr[0][1] = ((const f32x4*)kp)[1];
        const float* kp1 = kp + 32 * HDIM;
        kr[1][0] = ((const f32x4*)kp1)[0];
        kr[1][1] = ((const f32x4*)kp1)[1];
        const float* vp = Vg + base + (long)(t * KVBLK + vkb * 4) * HDIM + vcb * 4;
        #pragma unroll
        for (int j = 0; j < 4; ++j) vr[j] = ((const f32x4*)(vp + j * HDIM))[0];
    };
    auto STORET = [&](int b) {
        #pragma unroll
        for (int p = 0; p < 2; ++p) {
            const int row = krow + 32 * p;
            uint4v w;
            w[0] = cvtpk(kr[p][0][0], kr[p][0][1]);
            w[1] = cvtpk(kr[p][0][2], kr[p][0][3]);
            w[2] = cvtpk(kr[p][1][0], kr[p][1][1]);
            w[3] = cvtpk(kr[p][1][2], kr[p][1][3]);
            *(uint4v*)&Kl[b][row * 64 + ((kslot ^ (row & 7)) * 8)] = w;
        }
        #pragma unroll
        for (int i = 0; i < 4; ++i) {
            const int row = vcb * 4 + i;
            uint2v w;
            w[0] = cvtpk(vr[0][i], vr[1][i]);
            w[1] = cvtpk(vr[2][i], vr[3][i]);
            *(uint2v*)&Vt[b][row * 64 + (((vkb >> 1) ^ (row & 7)) * 8) + (vkb & 1) * 4] = w;
        }
    };

    LOADT(0);
    STORET(0);
    LOADT(1);
    __syncthreads();

    for (int t = 0; t < NT; ++t) {
        const int cur = t & 1;
        if (t + 1 < NT) {
            STORET(cur ^ 1);
            if (t + 2 < NT) LOADT(t + 2);
        }

        f32x16 sacc[2];
        #pragma unroll
        for (int mt = 0; mt < 2; ++mt)
            #pragma unroll
            for (int r = 0; r < 16; ++r) sacc[mt][r] = 0.f;
        #pragma unroll
        for (int mt = 0; mt < 2; ++mt) {
            #pragma unroll
            for (int kc = 0; kc < 4; ++kc) {
                short8 ka = *(const short8*)&Kl[cur][(mt * 32 + n) * 64 + (((2 * kc + hi) ^ n7) * 8)];
                sacc[mt] = MFMA32(ka, qf[kc], sacc[mt]);
            }
        }

        float pm = fmaxf(max16(sacc[0]), max16(sacc[1]));
        pm = fmaxf(pm, __shfl_xor(pm, 32));
        if (!__all(pm - mrun <= 8.f)) {
            const float mnew = fmaxf(mrun, pm);
            const float corr = __builtin_amdgcn_exp2f(mrun - mnew);
            mrun = mnew;
            lrun *= corr;
            #pragma unroll
            for (int r = 0; r < 16; ++r) {
                const int qoff = (r & 3) + 8 * (r >> 2) + 4 * hi;
                const float cR = __shfl(corr, qoff);
                oacc[0][r] *= cR;
                oacc[1][r] *= cR;
            }
        }
        float rs[4] = {0.f, 0.f, 0.f, 0.f};
        #pragma unroll
        for (int mt = 0; mt < 2; ++mt)
            #pragma unroll
            for (int r = 0; r < 16; ++r) {
                float p = __builtin_amdgcn_exp2f(sacc[mt][r] - mrun);
                sacc[mt][r] = p;
                rs[r & 3] += p;
            }
        float rsum = (rs[0] + rs[1]) + (rs[2] + rs[3]);
        rsum += __shfl_xor(rsum, 32);
        lrun += rsum;

        bf16x8 pa[4];
        #pragma unroll
        for (int mt = 0; mt < 2; ++mt) {
            #pragma unroll
            for (int ksl = 0; ksl < 2; ++ksl) {
                uint4v W;
                #pragma unroll
                for (int tt = 0; tt < 2; ++tt) {
                    unsigned X = cvtpk(sacc[mt][8 * ksl + 2 * tt],     sacc[mt][8 * ksl + 2 * tt + 1]);
                    unsigned Y = cvtpk(sacc[mt][8 * ksl + 4 + 2 * tt], sacc[mt][8 * ksl + 4 + 2 * tt + 1]);
                    unsigned sx = __shfl_xor(X, 32);
                    unsigned sy = __shfl_xor(Y, 32);
                    W[tt]     = hi ? sy : X;
                    W[2 + tt] = hi ? Y  : sx;
                }
                pa[mt * 2 + ksl] = __builtin_bit_cast(bf16x8, W);
            }
        }

        #pragma unroll
        for (int nt = 0; nt < 2; ++nt) {
            #pragma unroll
            for (int ks = 0; ks < 4; ++ks) {
                short8 vb = *(const short8*)&Vt[cur][(nt * 32 + n) * 64 + (((2 * ks + hi) ^ n7) * 8)];
                oacc[nt] = MFMA32(pa[ks], vb, oacc[nt]);
            }
        }
        __syncthreads();
    }

    const float linv = 1.f / lrun;
    #pragma unroll
    for (int r = 0; r < 16; ++r) {
        const int qoff = (r & 3) + 8 * (r >> 2) + 4 * hi;
        const float li = __shfl(linv, qoff);
        float* op = Og + base + (long)(q0 + qoff) * HDIM + n;
        op[0]  = oacc[0][r] * li;
        op[32] = oacc[1][r] * li;
    }
}

extern "C" void kernel_launch(void* const* d_in, const int* in_sizes, int n_in,
                              void* d_out, int out_size, void* d_ws, size_t ws_size,
                              hipStream_t stream) {
    const float* Q = (const float*)d_in[0];
    const float* K = (const float*)d_in[1];
    const float* V = (const float*)d_in[2];
    float* O = (float*)d_out;
    const int bh = in_sizes[0] / (T_SEQ * HDIM);   // 16
    const size_t elems = (size_t)bh * T_SEQ * HDIM;
    const size_t need  = 2 * elems * sizeof(short);

    dim3 grid(T_SEQ / QBLK, bh);
    if (d_ws != nullptr && ws_size >= need) {
        short* Kb  = (short*)d_ws;
        short* Vtb = Kb + elems;
        cvt_k <<<dim3(elems / (8 * 256)), 256, 0, stream>>>(K, Kb);
        cvt_vt<<<dim3(T_SEQ / 64, bh), 256, 0, stream>>>(V, Vtb);
        attn_fwd2<<<grid, 256, 0, stream>>>(Q, Kb, Vtb, O);
    } else {
        attn_fwd_fb<<<grid, 256, 0, stream>>>(Q, K, V, O);
    }
}